// Round 3
// baseline (241.700 us; speedup 1.0000x reference)
//
#include <hip/hip_runtime.h>
#include <math.h>
#include <stdint.h>

#define P_TOT 8192
#define CDIM  256
#define KC    50
#define NPIX  1024
#define TI    32

// MFMA pass geometry: 64 ano-rows/block (4 waves x 16), 8 j-splits, 32-col tiles
#define RPB   64
#define JSP   8
#define JCH   (P_TOT / JSP)   // 1024
#define JST   32
#define NJS   (JCH / JST)     // 32

// workspace float offsets
#define OFF_NRM   0         // [8192]
#define OFF_Z     8192      // [8192]
#define OFF_S2    16384     // [8192]
#define OFF_THR   24576     // [8192]
#define OFF_DEN   32768     // [8192]
#define OFF_SCAL  40960     // [64] 0=sum_d_nor 1=sum_d_ano
#define OFF_C2    41024     // [64]
#define OFF_CT    41088     // [12800] centers^T [c][k]
#define OFF_NFLAG 53888     // [8192] 1.0 if normal else 0.0
#define OFF_XNB   65536     // [8192][256] bf16 normalized (1M floats)
#define OFF_XTB   1114112   // [256][8192] bf16 raw X^T    (1M floats)
#define OFF_OUT   2162688   // [8192][256] f32 numerator accum
#define IOFF_BASE 4259840
#define II_ANOIDX 0
#define II_M      8192
#define II_CNTANO 8193
#define II_FLAGS  8200

typedef __attribute__((ext_vector_type(8))) short short8;
typedef __attribute__((ext_vector_type(4))) float f32x4;

__device__ __forceinline__ ushort f2bf(float x) {
    union { float f; unsigned u; } v; v.f = x;
    unsigned r = v.u + 0x7fffu + ((v.u >> 16) & 1u);
    return (ushort)(r >> 16);
}
__device__ __forceinline__ float bf2f(ushort h) {
    union { unsigned u; float f; } v; v.u = ((unsigned)h) << 16;
    return v.f;
}

typedef const __attribute__((address_space(1))) void gas_void;
typedef __attribute__((address_space(3))) void las_void;
__device__ __forceinline__ void gld_lds16(const void* g, void* l) {
    __builtin_amdgcn_global_load_lds(
        (gas_void*)(unsigned long long)(uintptr_t)g,
        (las_void*)(unsigned int)(uintptr_t)l, 16, 0, 0);
}

__global__ void k0_prep(const float* __restrict__ center, float* __restrict__ wsF) {
    int tid = threadIdx.x;
    float* cT = wsF + OFF_CT;
    float* c2 = wsF + OFF_C2;
    for (int idx = tid; idx < KC * CDIM; idx += 256) {
        int k = idx / CDIM, c = idx % CDIM;
        cT[c * KC + k] = center[idx];
    }
    if (tid < KC) {
        float s = 0.f;
        for (int c = 0; c < CDIM; ++c) { float v = center[tid * CDIM + c]; s += v * v; }
        c2[tid] = s;
    }
}

// centers read via wave-uniform indices -> scalar loads, no LDS
__global__ __launch_bounds__(256) void k1_dist(const float* __restrict__ f,
                                               const float* __restrict__ TcP,
                                               const float* __restrict__ cT,
                                               const float* __restrict__ c2g,
                                               float* __restrict__ wsF,
                                               int* __restrict__ wsI) {
    int tid = threadIdx.x;
    int p = blockIdx.x * 256 + tid;
    int b = p >> 10, n = p & 1023;
    const float* fp = f + (size_t)b * CDIM * NPIX + n;

    float acc[KC];
#pragma unroll
    for (int k = 0; k < KC; ++k) acc[k] = 0.f;
    float x2 = 0.f;
    for (int c = 0; c < CDIM; ++c) {
        float xv = fp[(size_t)c * NPIX];
        x2 += xv * xv;
        const float* ct = cT + c * KC;
#pragma unroll
        for (int k = 0; k < KC; ++k) acc[k] = fmaf(xv, ct[k], acc[k]);
    }
    float d2m = 3.4e38f;
#pragma unroll
    for (int k = 0; k < KC; ++k) {
        float d2 = x2 + c2g[k] - 2.f * acc[k];
        d2m = fminf(d2m, d2);
    }
    float d = sqrtf(fmaxf(d2m, 0.f));
    bool ano = d > TcP[0];
    wsF[OFF_NRM + p] = fmaxf(sqrtf(x2), 1e-8f);
    wsF[OFF_NFLAG + p] = ano ? 0.f : 1.f;
    wsI[II_FLAGS + p] = ano ? 1 : 0;

    float dn = ano ? 0.f : d;
    float da = ano ? d : 0.f;
    for (int o = 32; o >= 1; o >>= 1) { dn += __shfl_down(dn, o); da += __shfl_down(da, o); }
    int lane = tid & 63;
    unsigned long long mask = __ballot(ano);
    int cnt = __popcll(mask);
    if (lane == 0) {
        atomicAdd(&wsF[OFF_SCAL + 0], dn);
        atomicAdd(&wsF[OFF_SCAL + 1], da);
        if (cnt) atomicAdd(&wsI[II_CNTANO], cnt);
    }
    if (ano) {
        int leader = __ffsll((unsigned long long)mask) - 1;
        int base = 0;
        if (lane == leader) base = atomicAdd(&wsI[II_M], cnt);
        base = __shfl(base, leader);
        int off = __popcll(mask & ((1ull << lane) - 1ull));
        wsI[II_ANOIDX + base + off] = p;
    }
}

// f [b][c][n] fp32 -> XnB [p][c] bf16 normalized, XTB [c][p] bf16 raw
__global__ void k2_convert(const float* __restrict__ f, float* __restrict__ wsF) {
    __shared__ float t[32][33];
    int b = blockIdx.z, n0 = blockIdx.x * 32, c0 = blockIdx.y * 32;
    int tx = threadIdx.x, ty = threadIdx.y;
    const float* src = f + ((size_t)b * CDIM + c0) * NPIX + n0;
    ushort* XnB = (ushort*)(wsF + OFF_XNB);
    ushort* XTB = (ushort*)(wsF + OFF_XTB);
#pragma unroll
    for (int r = 0; r < 32; r += 8) {
        float v = src[(size_t)(ty + r) * NPIX + tx];
        t[ty + r][tx] = v;
        XTB[(size_t)(c0 + ty + r) * P_TOT + b * NPIX + n0 + tx] = f2bf(v);
    }
    __syncthreads();
#pragma unroll
    for (int r = 0; r < 32; r += 8) {
        int p = b * NPIX + n0 + ty + r;
        float nrm = wsF[OFF_NRM + p];
        XnB[(size_t)p * CDIM + c0 + tx] = f2bf(t[tx][ty + r] / nrm);
    }
}

__global__ void k3_copy(const float* __restrict__ f, float* __restrict__ out,
                        const float* __restrict__ wsF, const int* __restrict__ wsI) {
    int gid = blockIdx.x * blockDim.x + threadIdx.x;
    const float4* src = (const float4*)f;
    float4* dst = (float4*)out;
    int total = P_TOT * CDIM / 4;
    for (int i = gid; i < total; i += gridDim.x * blockDim.x) dst[i] = src[i];
    if (gid == 0) {
        int cntAno = wsI[II_CNTANO];
        float cntNor = (float)(P_TOT - cntAno);
        float meanNor = wsF[OFF_SCAL + 0] / fmaxf(cntNor, 1.f);
        float meanAno = wsF[OFF_SCAL + 1] / fmaxf((float)cntAno, 1.f);
        out[P_TOT * CDIM] = (cntAno > 0) ? meanNor / (meanAno + 0.001f) : meanNor;
    }
}

// pass1: Z = sum_nor exp(s-1), S2 = sum exp^2 via MFMA; double-buffered DMA staging
__global__ __launch_bounds__(256, 2) void k5a(float* __restrict__ wsF, const int* __restrict__ wsI) {
    const int Mv = wsI[II_M];
    const int i0 = blockIdx.x * RPB;
    if (i0 >= Mv) return;
    __shared__ __align__(16) ushort sK[2][JST * CDIM];   // 2 x 16KB
    const int tid = threadIdx.x;
    const int wave = tid >> 6, lane = tid & 63;
    const int lrow = lane & 15, lgrp = lane >> 4;
    const char* XnBb = (const char*)(wsF + OFF_XNB);
    const float* nflag = wsF + OFF_NFLAG;
    const int* anoIdx = wsI + II_ANOIDX;
    const int jc0 = blockIdx.y * JCH;
    const int iw = i0 + wave * 16;

    short8 qf[8];
    {
        int arow = anoIdx[min(iw + lrow, Mv - 1)];
        const ushort* qp = (const ushort*)XnBb + (size_t)arow * CDIM + lgrp * 8;
#pragma unroll
        for (int kc = 0; kc < 8; ++kc) qf[kc] = *(const short8*)(qp + kc * 32);
    }
    float zAcc[4], s2Acc[4];
#pragma unroll
    for (int r = 0; r < 4; ++r) { zAcc[r] = 0.f; s2Acc[r] = 0.f; }

    auto stageK = [&](int buf, int j0) {
#pragma unroll
        for (int it = 0; it < 4; ++it) {
            int chunk = (wave << 2) + it;
            int d = (chunk << 10) + (lane << 4);
            int row = d >> 9;
            int srco = (d & ~511) | ((d & 511) ^ ((row & 7) << 4));
            gld_lds16(XnBb + ((size_t)j0 << 9) + srco, (char*)sK[buf] + (chunk << 10));
        }
    };

    stageK(0, jc0);
    __syncthreads();
    int cur = 0;
    for (int js = 0; js < NJS; ++js) {
        int j0 = jc0 + js * JST;
        if (js + 1 < NJS) stageK(cur ^ 1, j0 + JST);
        float mf0 = nflag[j0 + lrow];
        float mf1 = nflag[j0 + 16 + lrow];
        f32x4 acc0 = {0.f, 0.f, 0.f, 0.f}, acc1 = {0.f, 0.f, 0.f, 0.f};
#pragma unroll
        for (int kc = 0; kc < 8; ++kc) {
            int cb = (kc << 6) + (lgrp << 4);
            int b0 = lrow * 512 + (cb ^ ((lrow & 7) << 4));
            int b1 = (16 + lrow) * 512 + (cb ^ (((16 + lrow) & 7) << 4));
            short8 bf0 = *(const short8*)((const char*)sK[cur] + b0);
            short8 bf1 = *(const short8*)((const char*)sK[cur] + b1);
            acc0 = __builtin_amdgcn_mfma_f32_16x16x32_bf16(qf[kc], bf0, acc0, 0, 0, 0);
            acc1 = __builtin_amdgcn_mfma_f32_16x16x32_bf16(qf[kc], bf1, acc1, 0, 0, 0);
        }
#pragma unroll
        for (int r = 0; r < 4; ++r) {
            float e0 = __expf(acc0[r] - 1.f) * mf0;
            float e1 = __expf(acc1[r] - 1.f) * mf1;
            zAcc[r] += e0 + e1;
            s2Acc[r] += e0 * e0 + e1 * e1;
        }
        __syncthreads();
        cur ^= 1;
    }
#pragma unroll
    for (int r = 0; r < 4; ++r) {
        float z = zAcc[r], q = s2Acc[r];
        for (int m = 8; m >= 1; m >>= 1) { z += __shfl_xor(z, m); q += __shfl_xor(q, m); }
        if (lrow == 0) {
            int i = iw + lgrp * 4 + r;
            if (i < Mv) { atomicAdd(&wsF[OFF_Z + i], z); atomicAdd(&wsF[OFF_S2 + i], q); }
        }
    }
}

__global__ void k4b_thr(float* __restrict__ wsF, const int* __restrict__ wsI) {
    int Mv = wsI[II_M];
    int idx = blockIdx.x * 256 + threadIdx.x;
    if (idx >= Mv) return;
    float t = fmaxf((float)(P_TOT - wsI[II_CNTANO]), 1.f);
    float Z = wsF[OFF_Z + idx], S2 = wsF[OFF_S2 + idx];
    float mu = 1.f / t;
    float var = S2 / (Z * Z * t) - mu * mu;
    wsF[OFF_THR + idx] = mu - 2.f * sqrtf(fmaxf(var, 0.f));
}

// pass2: sim -> sw -> (sw @ X), double-buffered DMA staging, paired-row X^T tile
__global__ __launch_bounds__(256, 2) void k5c(float* __restrict__ wsF, const int* __restrict__ wsI) {
    const int Mv = wsI[II_M];
    const int i0 = blockIdx.x * RPB;
    if (i0 >= Mv) return;
    __shared__ __align__(16) ushort sK[2][JST * CDIM];    // 2 x 16KB  [j][c] swz (r&7)<<4 on 512B rows
    __shared__ __align__(16) ushort sXT[2][CDIM * JST];   // 2 x 16KB  paired rows [128][128B] swz (R&7)<<4
    __shared__ __align__(16) ushort sSW[4][16 * JST];     // 4 x 1KB per-wave [16][64B] swz (i&3)<<4
    const int tid = threadIdx.x;
    const int wave = tid >> 6, lane = tid & 63;
    const int lrow = lane & 15, lgrp = lane >> 4;
    const char* XnBb = (const char*)(wsF + OFF_XNB);
    const char* XTBb = (const char*)(wsF + OFF_XTB);
    const float* nflag = wsF + OFF_NFLAG;
    const int* anoIdx = wsI + II_ANOIDX;
    const int jc0 = blockIdx.y * JCH;
    const int iw = i0 + wave * 16;

    short8 qf[8];
    {
        int arow = anoIdx[min(iw + lrow, Mv - 1)];
        const ushort* qp = (const ushort*)XnBb + (size_t)arow * CDIM + lgrp * 8;
#pragma unroll
        for (int kc = 0; kc < 8; ++kc) qf[kc] = *(const short8*)(qp + kc * 32);
    }
    float rz[4], thr[4], den[4];
#pragma unroll
    for (int r = 0; r < 4; ++r) {
        int i = min(iw + lgrp * 4 + r, Mv - 1);
        rz[r] = 1.f / wsF[OFF_Z + i];
        thr[r] = wsF[OFF_THR + i];
        den[r] = 0.f;
    }
    f32x4 oAcc[16];
#pragma unroll
    for (int ct = 0; ct < 16; ++ct) oAcc[ct] = (f32x4){0.f, 0.f, 0.f, 0.f};

    auto stageK = [&](int buf, int j0) {
#pragma unroll
        for (int it = 0; it < 4; ++it) {
            int chunk = (wave << 2) + it;
            int d = (chunk << 10) + (lane << 4);
            int row = d >> 9;
            int srco = (d & ~511) | ((d & 511) ^ ((row & 7) << 4));
            gld_lds16(XnBb + ((size_t)j0 << 9) + srco, (char*)sK[buf] + (chunk << 10));
        }
    };
    auto stageX = [&](int buf, int j0) {
#pragma unroll
        for (int it = 0; it < 4; ++it) {
            int chunk = (wave << 2) + it;
            int d = (chunk << 10) + (lane << 4);
            int R = d >> 7;
            int q = (d & 127) ^ ((R & 7) << 4);
            int c = 2 * R + (q >> 6);
            gld_lds16(XTBb + (size_t)c * (P_TOT * 2) + ((size_t)j0 << 1) + (q & 63),
                      (char*)sXT[buf] + (chunk << 10));
        }
    };

    stageK(0, jc0);
    stageX(0, jc0);
    __syncthreads();
    int cur = 0;
    ushort* msw = (ushort*)sSW[wave];
    for (int js = 0; js < NJS; ++js) {
        int j0 = jc0 + js * JST;
        if (js + 1 < NJS) { stageK(cur ^ 1, j0 + JST); stageX(cur ^ 1, j0 + JST); }
        float mf0 = nflag[j0 + lrow];
        float mf1 = nflag[j0 + 16 + lrow];
        f32x4 acc0 = {0.f, 0.f, 0.f, 0.f}, acc1 = {0.f, 0.f, 0.f, 0.f};
#pragma unroll
        for (int kc = 0; kc < 8; ++kc) {
            int cb = (kc << 6) + (lgrp << 4);
            int b0 = lrow * 512 + (cb ^ ((lrow & 7) << 4));
            int b1 = (16 + lrow) * 512 + (cb ^ (((16 + lrow) & 7) << 4));
            short8 bf0 = *(const short8*)((const char*)sK[cur] + b0);
            short8 bf1 = *(const short8*)((const char*)sK[cur] + b1);
            acc0 = __builtin_amdgcn_mfma_f32_16x16x32_bf16(qf[kc], bf0, acc0, 0, 0, 0);
            acc1 = __builtin_amdgcn_mfma_f32_16x16x32_bf16(qf[kc], bf1, acc1, 0, 0, 0);
        }
#pragma unroll
        for (int r = 0; r < 4; ++r) {
            int irow = lgrp * 4 + r;
            {
                float w = __expf(acc0[r] - 1.f) * mf0 * rz[r];
                float dd = w - thr[r];
                float sw = fmaxf(dd, 0.f) * w / (fabsf(dd) + 1e-10f);
                ushort h = f2bf(sw);
                den[r] += bf2f(h);
                *(ushort*)((char*)msw + irow * 64 + ((2 * lrow) ^ ((irow & 3) << 4))) = h;
            }
            {
                float w = __expf(acc1[r] - 1.f) * mf1 * rz[r];
                float dd = w - thr[r];
                float sw = fmaxf(dd, 0.f) * w / (fabsf(dd) + 1e-10f);
                ushort h = f2bf(sw);
                den[r] += bf2f(h);
                *(ushort*)((char*)msw + irow * 64 + ((2 * (16 + lrow)) ^ ((irow & 3) << 4))) = h;
            }
        }
        short8 aF = *(const short8*)((const char*)msw + lrow * 64 + ((lgrp << 4) ^ ((lrow & 3) << 4)));
#pragma unroll
        for (int ct = 0; ct < 16; ++ct) {
            int crow = ct * 16 + lrow;
            int R = crow >> 1;
            int off = (((crow & 1) << 6) + (lgrp << 4)) ^ ((R & 7) << 4);
            short8 bf = *(const short8*)((const char*)sXT[cur] + R * 128 + off);
            oAcc[ct] = __builtin_amdgcn_mfma_f32_16x16x32_bf16(aF, bf, oAcc[ct], 0, 0, 0);
        }
        __syncthreads();
        cur ^= 1;
    }

#pragma unroll
    for (int r = 0; r < 4; ++r) {
        float dv = den[r];
        for (int m = 8; m >= 1; m >>= 1) dv += __shfl_xor(dv, m);
        int i = iw + lgrp * 4 + r;
        if (lrow == 0 && i < Mv) atomicAdd(&wsF[OFF_DEN + i], dv);
        if (i < Mv) {
            float* go = wsF + OFF_OUT + (size_t)i * CDIM + lrow;
#pragma unroll
            for (int ct = 0; ct < 16; ++ct) atomicAdd(&go[ct * 16], oAcc[ct][r]);
        }
    }
}

__global__ void k4d_final(float* __restrict__ out, const float* __restrict__ wsF,
                          const int* __restrict__ wsI) {
    int Mv = wsI[II_M];
    int i0 = blockIdx.x * TI;
    if (i0 >= Mv) return;
    int tid = threadIdx.x;
    int ii = tid >> 3, cg = tid & 7;
    int i = i0 + ii;
    if (i >= Mv) return;
    int p = wsI[II_ANOIDX + i];
    int b = p >> 10, n = p & 1023;
    float rden = 1.f / wsF[OFF_DEN + i];
    const float* go = wsF + OFF_OUT + (size_t)i * CDIM;
    float* op = out + (size_t)b * CDIM * NPIX + n;
#pragma unroll
    for (int cc = 0; cc < 32; ++cc) {
        int c = cc * 8 + cg;
        op[(size_t)c * NPIX] = go[c] * rden;
    }
}

extern "C" void kernel_launch(void* const* d_in, const int* in_sizes, int n_in,
                              void* d_out, int out_size, void* d_ws, size_t ws_size,
                              hipStream_t stream) {
    const float* f = (const float*)d_in[0];
    const float* center = (const float*)d_in[1];
    const float* Tc = (const float*)d_in[2];
    float* out = (float*)d_out;
    float* wsF = (float*)d_ws;
    int* wsI = (int*)(wsF + IOFF_BASE);

    hipMemsetAsync(wsF + OFF_Z, 0, (OFF_CT - OFF_Z) * sizeof(float), stream);
    hipMemsetAsync(wsF + OFF_OUT, 0, (size_t)P_TOT * CDIM * sizeof(float), stream);
    hipMemsetAsync(wsI + II_M, 0, 2 * sizeof(int), stream);

    k0_prep<<<1, 256, 0, stream>>>(center, wsF);
    k1_dist<<<32, 256, 0, stream>>>(f, Tc, wsF + OFF_CT, wsF + OFF_C2, wsF, wsI);
    dim3 g2(32, 8, 8), b2(32, 8);
    k2_convert<<<g2, b2, 0, stream>>>(f, wsF);
    k3_copy<<<512, 256, 0, stream>>>(f, out, wsF, wsI);
    dim3 g5(P_TOT / RPB, JSP);
    k5a<<<g5, 256, 0, stream>>>(wsF, wsI);
    k4b_thr<<<P_TOT / 256, 256, 0, stream>>>(wsF, wsI);
    k5c<<<g5, 256, 0, stream>>>(wsF, wsI);
    k4d_final<<<P_TOT / TI, 256, 0, stream>>>(out, wsF, wsI);
}

// Round 4
// 184.275 us; speedup vs baseline: 1.3116x; 1.3116x over previous
//
#include <hip/hip_runtime.h>
#include <math.h>
#include <stdint.h>

#define P_TOT 8192
#define CDIM  256
#define KC    50
#define NPIX  1024
#define TI    32

// MFMA pass geometry
#define RPB   64
#define JSPA  16                 // j-splits for pass1
#define JCHA  (P_TOT / JSPA)     // 512
#define JSP   8                  // j-splits for pass2
#define JCH   (P_TOT / JSP)      // 1024
#define JST   32
#define NJS   (JCH / JST)        // 32
#define NJSA  (JCHA / JST)       // 16

// sK swizzle: row-pair XOR, keeps even-row and odd-row b128 reads 2-way
#define SWZK(row) ((((row) >> 1) & 7) << 4)

// workspace float offsets
#define OFF_NRM   0         // [8192]
#define OFF_Z     8192      // [8192]
#define OFF_S2    16384     // [8192]
#define OFF_THR   24576     // [8192]
#define OFF_DEN   32768     // [8192]
#define OFF_SCAL  40960     // [64] 0=sum_d_nor 1=sum_d_ano
#define OFF_C2    41024     // [64]
#define OFF_NFLAG 53888     // [8192] 1.0 if normal else 0.0
#define OFF_XNB   65536     // [8192][256] bf16 normalized (1M floats)
#define OFF_XTB   1114112   // [256][8192] bf16 raw X^T    (1M floats)
#define OFF_PART  65536     // [4][51][8192] f32 partial dot/x2 (aliases XNB, used before k2)
#define OFF_OUT   2162688   // [8192][256] f32 numerator accum
#define IOFF_BASE 4259840
#define II_ANOIDX 0
#define II_M      8192
#define II_CNTANO 8193
#define II_FLAGS  8200

typedef __attribute__((ext_vector_type(8))) short short8;
typedef __attribute__((ext_vector_type(4))) float f32x4;

__device__ __forceinline__ ushort f2bf(float x) {
    union { float f; unsigned u; } v; v.f = x;
    unsigned r = v.u + 0x7fffu + ((v.u >> 16) & 1u);
    return (ushort)(r >> 16);
}
__device__ __forceinline__ float bf2f(ushort h) {
    union { unsigned u; float f; } v; v.u = ((unsigned)h) << 16;
    return v.f;
}

typedef const __attribute__((address_space(1))) void gas_void;
typedef __attribute__((address_space(3))) void las_void;
__device__ __forceinline__ void gld_lds16(const void* g, void* l) {
    __builtin_amdgcn_global_load_lds(
        (gas_void*)(unsigned long long)(uintptr_t)g,
        (las_void*)(unsigned int)(uintptr_t)l, 16, 0, 0);
}

// c2[k] = ||center_k||^2, 4 partial threads per k
__global__ void k0_prep(const float* __restrict__ center, float* __restrict__ wsF) {
    int tid = threadIdx.x;
    if (tid >= 200) return;
    int k = tid >> 2, q = tid & 3;
    float s = 0.f;
    const float* cp = center + k * CDIM + q * 64;
    for (int c = 0; c < 64; ++c) { float v = cp[c]; s += v * v; }
    s += __shfl_down(s, 2);
    s += __shfl_down(s, 1);
    if (q == 0) wsF[OFF_C2 + k] = s;
}

// stage 1 of distance: partial dot[50] + x2 over a 64-channel chunk
__global__ __launch_bounds__(256) void k1a_dot(const float* __restrict__ f,
                                               const float* __restrict__ center,
                                               float* __restrict__ PART) {
    int tid = threadIdx.x;
    int px = blockIdx.x * 256 + tid;
    int cg = blockIdx.y;             // 0..3
    int b = px >> 10, n = px & 1023;
    const float* fp = f + ((size_t)b * CDIM + cg * 64) * NPIX + n;
    float acc[KC];
#pragma unroll
    for (int k = 0; k < KC; ++k) acc[k] = 0.f;
    float x2 = 0.f;
    for (int cc = 0; cc < 64; ++cc) {
        float xv = fp[(size_t)cc * NPIX];
        x2 += xv * xv;
        const float* cp = center + (cg * 64 + cc);   // column c, wave-uniform -> s_loads
#pragma unroll
        for (int k = 0; k < KC; ++k) acc[k] = fmaf(xv, cp[(size_t)k * CDIM], acc[k]);
    }
    float* dst = PART + (size_t)cg * 51 * P_TOT + px;
#pragma unroll
    for (int k = 0; k < KC; ++k) dst[(size_t)k * P_TOT] = acc[k];
    dst[(size_t)50 * P_TOT] = x2;
}

// stage 2: fixed-order reduce, min over K, flags + compaction + Ld partials
__global__ __launch_bounds__(256) void k1b_min(const float* __restrict__ TcP,
                                               const float* __restrict__ c2g,
                                               const float* __restrict__ PART,
                                               float* __restrict__ wsF,
                                               int* __restrict__ wsI) {
    int tid = threadIdx.x;
    int px = blockIdx.x * 256 + tid;
    float x2 = 0.f;
#pragma unroll
    for (int g = 0; g < 4; ++g) x2 += PART[((size_t)g * 51 + 50) * P_TOT + px];
    float d2m = 3.4e38f;
#pragma unroll 10
    for (int k = 0; k < KC; ++k) {
        float s = PART[(size_t)k * P_TOT + px];
#pragma unroll
        for (int g = 1; g < 4; ++g) s += PART[((size_t)g * 51 + k) * P_TOT + px];
        float d2 = x2 + c2g[k] - 2.f * s;
        d2m = fminf(d2m, d2);
    }
    float d = sqrtf(fmaxf(d2m, 0.f));
    bool ano = d > TcP[0];
    wsF[OFF_NRM + px] = fmaxf(sqrtf(x2), 1e-8f);
    wsF[OFF_NFLAG + px] = ano ? 0.f : 1.f;
    wsI[II_FLAGS + px] = ano ? 1 : 0;

    float dn = ano ? 0.f : d;
    float da = ano ? d : 0.f;
    for (int o = 32; o >= 1; o >>= 1) { dn += __shfl_down(dn, o); da += __shfl_down(da, o); }
    int lane = tid & 63;
    unsigned long long mask = __ballot(ano);
    int cnt = __popcll(mask);
    if (lane == 0) {
        atomicAdd(&wsF[OFF_SCAL + 0], dn);
        atomicAdd(&wsF[OFF_SCAL + 1], da);
        if (cnt) atomicAdd(&wsI[II_CNTANO], cnt);
    }
    if (ano) {
        int leader = __ffsll((unsigned long long)mask) - 1;
        int base = 0;
        if (lane == leader) base = atomicAdd(&wsI[II_M], cnt);
        base = __shfl(base, leader);
        int off = __popcll(mask & ((1ull << lane) - 1ull));
        wsI[II_ANOIDX + base + off] = px;
    }
}

// f [b][c][n] fp32 -> XnB [p][c] bf16 normalized, XTB [c][p] bf16 raw
__global__ void k2_convert(const float* __restrict__ f, float* __restrict__ wsF) {
    __shared__ float t[32][33];
    int b = blockIdx.z, n0 = blockIdx.x * 32, c0 = blockIdx.y * 32;
    int tx = threadIdx.x, ty = threadIdx.y;
    const float* src = f + ((size_t)b * CDIM + c0) * NPIX + n0;
    ushort* XnB = (ushort*)(wsF + OFF_XNB);
    ushort* XTB = (ushort*)(wsF + OFF_XTB);
#pragma unroll
    for (int r = 0; r < 32; r += 8) {
        float v = src[(size_t)(ty + r) * NPIX + tx];
        t[ty + r][tx] = v;
        XTB[(size_t)(c0 + ty + r) * P_TOT + b * NPIX + n0 + tx] = f2bf(v);
    }
    __syncthreads();
#pragma unroll
    for (int r = 0; r < 32; r += 8) {
        int p = b * NPIX + n0 + ty + r;
        float nrm = wsF[OFF_NRM + p];
        XnB[(size_t)p * CDIM + c0 + tx] = f2bf(t[tx][ty + r] / nrm);
    }
}

__global__ void k3_copy(const float* __restrict__ f, float* __restrict__ out,
                        const float* __restrict__ wsF, const int* __restrict__ wsI) {
    int gid = blockIdx.x * blockDim.x + threadIdx.x;
    const float4* src = (const float4*)f;
    float4* dst = (float4*)out;
    int total = P_TOT * CDIM / 4;
    for (int i = gid; i < total; i += gridDim.x * blockDim.x) dst[i] = src[i];
    if (gid == 0) {
        int cntAno = wsI[II_CNTANO];
        float cntNor = (float)(P_TOT - cntAno);
        float meanNor = wsF[OFF_SCAL + 0] / fmaxf(cntNor, 1.f);
        float meanAno = wsF[OFF_SCAL + 1] / fmaxf((float)cntAno, 1.f);
        out[P_TOT * CDIM] = (cntAno > 0) ? meanNor / (meanAno + 0.001f) : meanNor;
    }
}

// pass1: Z = sum_nor exp(s-1), S2 = sum exp^2 via MFMA; dbuf DMA staging; 4 blocks/CU
__global__ __launch_bounds__(256, 4) void k5a(float* __restrict__ wsF, const int* __restrict__ wsI) {
    const int Mv = wsI[II_M];
    const int i0 = blockIdx.x * RPB;
    if (i0 >= Mv) return;
    __shared__ __align__(16) ushort sK[2][JST * CDIM];   // 2 x 16KB
    const int tid = threadIdx.x;
    const int wave = tid >> 6, lane = tid & 63;
    const int lrow = lane & 15, lgrp = lane >> 4;
    const char* XnBb = (const char*)(wsF + OFF_XNB);
    const float* nflag = wsF + OFF_NFLAG;
    const int* anoIdx = wsI + II_ANOIDX;
    const int jc0 = blockIdx.y * JCHA;
    const int iw = i0 + wave * 16;

    short8 qf[8];
    {
        int arow = anoIdx[min(iw + lrow, Mv - 1)];
        const ushort* qp = (const ushort*)XnBb + (size_t)arow * CDIM + lgrp * 8;
#pragma unroll
        for (int kc = 0; kc < 8; ++kc) qf[kc] = *(const short8*)(qp + kc * 32);
    }
    float zAcc[4], s2Acc[4];
#pragma unroll
    for (int r = 0; r < 4; ++r) { zAcc[r] = 0.f; s2Acc[r] = 0.f; }

    auto stageK = [&](int buf, int j0) {
#pragma unroll
        for (int it = 0; it < 4; ++it) {
            int chunk = (wave << 2) + it;
            int d = (chunk << 10) + (lane << 4);
            int row = d >> 9;
            int srco = (d & ~511) | ((d & 511) ^ SWZK(row));
            gld_lds16(XnBb + ((size_t)j0 << 9) + srco, (char*)sK[buf] + (chunk << 10));
        }
    };

    stageK(0, jc0);
    __syncthreads();
    int cur = 0;
    for (int js = 0; js < NJSA; ++js) {
        int j0 = jc0 + js * JST;
        if (js + 1 < NJSA) stageK(cur ^ 1, j0 + JST);
        float mf0 = nflag[j0 + lrow];
        float mf1 = nflag[j0 + 16 + lrow];
        f32x4 acc0 = {0.f, 0.f, 0.f, 0.f}, acc1 = {0.f, 0.f, 0.f, 0.f};
#pragma unroll
        for (int kc = 0; kc < 8; ++kc) {
            int cb = (kc << 6) + (lgrp << 4);
            int b0 = lrow * 512 + (cb ^ SWZK(lrow));
            int b1 = (16 + lrow) * 512 + (cb ^ SWZK(16 + lrow));
            short8 bf0 = *(const short8*)((const char*)sK[cur] + b0);
            short8 bf1 = *(const short8*)((const char*)sK[cur] + b1);
            acc0 = __builtin_amdgcn_mfma_f32_16x16x32_bf16(qf[kc], bf0, acc0, 0, 0, 0);
            acc1 = __builtin_amdgcn_mfma_f32_16x16x32_bf16(qf[kc], bf1, acc1, 0, 0, 0);
        }
#pragma unroll
        for (int r = 0; r < 4; ++r) {
            float e0 = __expf(acc0[r] - 1.f) * mf0;
            float e1 = __expf(acc1[r] - 1.f) * mf1;
            zAcc[r] += e0 + e1;
            s2Acc[r] += e0 * e0 + e1 * e1;
        }
        __syncthreads();
        cur ^= 1;
    }
#pragma unroll
    for (int r = 0; r < 4; ++r) {
        float z = zAcc[r], q = s2Acc[r];
        for (int m = 8; m >= 1; m >>= 1) { z += __shfl_xor(z, m); q += __shfl_xor(q, m); }
        if (lrow == 0) {
            int i = iw + lgrp * 4 + r;
            if (i < Mv) { atomicAdd(&wsF[OFF_Z + i], z); atomicAdd(&wsF[OFF_S2 + i], q); }
        }
    }
}

__global__ void k4b_thr(float* __restrict__ wsF, const int* __restrict__ wsI) {
    int Mv = wsI[II_M];
    int idx = blockIdx.x * 256 + threadIdx.x;
    if (idx >= Mv) return;
    float t = fmaxf((float)(P_TOT - wsI[II_CNTANO]), 1.f);
    float Z = wsF[OFF_Z + idx], S2 = wsF[OFF_S2 + idx];
    float mu = 1.f / t;
    float var = S2 / (Z * Z * t) - mu * mu;
    wsF[OFF_THR + idx] = mu - 2.f * sqrtf(fmaxf(var, 0.f));
}

// pass2: sim -> sw -> (sw @ X); adjacent-j lane pairs, packed u32 sSW writes
__global__ __launch_bounds__(256, 2) void k5c(float* __restrict__ wsF, const int* __restrict__ wsI) {
    const int Mv = wsI[II_M];
    const int i0 = blockIdx.x * RPB;
    if (i0 >= Mv) return;
    __shared__ __align__(16) ushort sK[2][JST * CDIM];    // 2 x 16KB
    __shared__ __align__(16) ushort sXT[2][CDIM * JST];   // 2 x 16KB paired-row [128][128B] swz (R&7)<<4
    __shared__ __align__(16) char sSW[4][16 * 144];       // per-wave [16 i][32 j]x2B, 144B stride
    const int tid = threadIdx.x;
    const int wave = tid >> 6, lane = tid & 63;
    const int lrow = lane & 15, lgrp = lane >> 4;
    const char* XnBb = (const char*)(wsF + OFF_XNB);
    const char* XTBb = (const char*)(wsF + OFF_XTB);
    const float* nflag = wsF + OFF_NFLAG;
    const int* anoIdx = wsI + II_ANOIDX;
    const int jc0 = blockIdx.y * JCH;
    const int iw = i0 + wave * 16;

    short8 qf[8];
    {
        int arow = anoIdx[min(iw + lrow, Mv - 1)];
        const ushort* qp = (const ushort*)XnBb + (size_t)arow * CDIM + lgrp * 8;
#pragma unroll
        for (int kc = 0; kc < 8; ++kc) qf[kc] = *(const short8*)(qp + kc * 32);
    }
    float rz[4], thr[4], den[4];
#pragma unroll
    for (int r = 0; r < 4; ++r) {
        int i = min(iw + lgrp * 4 + r, Mv - 1);
        rz[r] = 1.f / wsF[OFF_Z + i];
        thr[r] = wsF[OFF_THR + i];
        den[r] = 0.f;
    }
    f32x4 oAcc[16];
#pragma unroll
    for (int ct = 0; ct < 16; ++ct) oAcc[ct] = (f32x4){0.f, 0.f, 0.f, 0.f};

    auto stageK = [&](int buf, int j0) {
#pragma unroll
        for (int it = 0; it < 4; ++it) {
            int chunk = (wave << 2) + it;
            int d = (chunk << 10) + (lane << 4);
            int row = d >> 9;
            int srco = (d & ~511) | ((d & 511) ^ SWZK(row));
            gld_lds16(XnBb + ((size_t)j0 << 9) + srco, (char*)sK[buf] + (chunk << 10));
        }
    };
    auto stageX = [&](int buf, int j0) {
#pragma unroll
        for (int it = 0; it < 4; ++it) {
            int chunk = (wave << 2) + it;
            int d = (chunk << 10) + (lane << 4);
            int R = d >> 7;
            int q = (d & 127) ^ ((R & 7) << 4);
            int c = 2 * R + (q >> 6);
            gld_lds16(XTBb + (size_t)c * (P_TOT * 2) + ((size_t)j0 << 1) + (q & 63),
                      (char*)sXT[buf] + (chunk << 10));
        }
    };

    stageK(0, jc0);
    stageX(0, jc0);
    __syncthreads();
    int cur = 0;
    char* msw = sSW[wave];
    for (int js = 0; js < NJS; ++js) {
        int j0 = jc0 + js * JST;
        if (js + 1 < NJS) { stageK(cur ^ 1, j0 + JST); stageX(cur ^ 1, j0 + JST); }
        float2 mfp = *(const float2*)&nflag[j0 + 2 * lrow];
        f32x4 acc0 = {0.f, 0.f, 0.f, 0.f}, acc1 = {0.f, 0.f, 0.f, 0.f};
#pragma unroll
        for (int kc = 0; kc < 8; ++kc) {
            int cb = (kc << 6) + (lgrp << 4);
            int b0 = (2 * lrow) * 512 + (cb ^ SWZK(2 * lrow));
            int b1 = (2 * lrow + 1) * 512 + (cb ^ SWZK(2 * lrow + 1));
            short8 bf0 = *(const short8*)((const char*)sK[cur] + b0);
            short8 bf1 = *(const short8*)((const char*)sK[cur] + b1);
            acc0 = __builtin_amdgcn_mfma_f32_16x16x32_bf16(qf[kc], bf0, acc0, 0, 0, 0);
            acc1 = __builtin_amdgcn_mfma_f32_16x16x32_bf16(qf[kc], bf1, acc1, 0, 0, 0);
        }
        // acc0 col r-lane maps to j = j0 + 2*lrow, acc1 -> j0 + 2*lrow + 1
#pragma unroll
        for (int r = 0; r < 4; ++r) {
            int irow = lgrp * 4 + r;
            float w0 = __expf(acc0[r] - 1.f) * mfp.x * rz[r];
            float d0 = w0 - thr[r];
            float sw0 = fmaxf(d0, 0.f) * w0 / (fabsf(d0) + 1e-10f);
            float w1 = __expf(acc1[r] - 1.f) * mfp.y * rz[r];
            float d1 = w1 - thr[r];
            float sw1 = fmaxf(d1, 0.f) * w1 / (fabsf(d1) + 1e-10f);
            ushort h0 = f2bf(sw0), h1 = f2bf(sw1);
            den[r] += bf2f(h0) + bf2f(h1);
            *(unsigned*)(msw + irow * 144 + 4 * lrow) = ((unsigned)h1 << 16) | (unsigned)h0;
        }
        short8 aF = *(const short8*)(msw + lrow * 144 + lgrp * 16);
#pragma unroll
        for (int ct = 0; ct < 16; ++ct) {
            int crow = ct * 16 + lrow;
            int R = crow >> 1;
            int off = (((crow & 1) << 6) + (lgrp << 4)) ^ ((R & 7) << 4);
            short8 bf = *(const short8*)((const char*)sXT[cur] + R * 128 + off);
            oAcc[ct] = __builtin_amdgcn_mfma_f32_16x16x32_bf16(aF, bf, oAcc[ct], 0, 0, 0);
        }
        __syncthreads();
        cur ^= 1;
    }

#pragma unroll
    for (int r = 0; r < 4; ++r) {
        float dv = den[r];
        for (int m = 8; m >= 1; m >>= 1) dv += __shfl_xor(dv, m);
        int i = iw + lgrp * 4 + r;
        if (lrow == 0 && i < Mv) atomicAdd(&wsF[OFF_DEN + i], dv);
        if (i < Mv) {
            float* go = wsF + OFF_OUT + (size_t)i * CDIM + lrow;
#pragma unroll
            for (int ct = 0; ct < 16; ++ct) atomicAdd(&go[ct * 16], oAcc[ct][r]);
        }
    }
}

__global__ void k4d_final(float* __restrict__ out, const float* __restrict__ wsF,
                          const int* __restrict__ wsI) {
    int Mv = wsI[II_M];
    int i0 = blockIdx.x * TI;
    if (i0 >= Mv) return;
    int tid = threadIdx.x;
    int ii = tid >> 3, cg = tid & 7;
    int i = i0 + ii;
    if (i >= Mv) return;
    int p = wsI[II_ANOIDX + i];
    int b = p >> 10, n = p & 1023;
    float rden = 1.f / wsF[OFF_DEN + i];
    const float* go = wsF + OFF_OUT + (size_t)i * CDIM;
    float* op = out + (size_t)b * CDIM * NPIX + n;
#pragma unroll
    for (int cc = 0; cc < 32; ++cc) {
        int c = cc * 8 + cg;
        op[(size_t)c * NPIX] = go[c] * rden;
    }
}

extern "C" void kernel_launch(void* const* d_in, const int* in_sizes, int n_in,
                              void* d_out, int out_size, void* d_ws, size_t ws_size,
                              hipStream_t stream) {
    const float* f = (const float*)d_in[0];
    const float* center = (const float*)d_in[1];
    const float* Tc = (const float*)d_in[2];
    float* out = (float*)d_out;
    float* wsF = (float*)d_ws;
    int* wsI = (int*)(wsF + IOFF_BASE);

    hipMemsetAsync(wsF + OFF_Z, 0, (OFF_C2 + 64 - OFF_Z) * sizeof(float), stream);
    hipMemsetAsync(wsF + OFF_OUT, 0, (size_t)P_TOT * CDIM * sizeof(float), stream);
    hipMemsetAsync(wsI + II_M, 0, 2 * sizeof(int), stream);

    k0_prep<<<1, 256, 0, stream>>>(center, wsF);
    dim3 g1a(32, 4);
    k1a_dot<<<g1a, 256, 0, stream>>>(f, center, wsF + OFF_PART);
    k1b_min<<<32, 256, 0, stream>>>(Tc, wsF + OFF_C2, wsF + OFF_PART, wsF, wsI);
    dim3 g2(32, 8, 8), b2(32, 8);
    k2_convert<<<g2, b2, 0, stream>>>(f, wsF);
    k3_copy<<<512, 256, 0, stream>>>(f, out, wsF, wsI);
    dim3 g5a(P_TOT / RPB, JSPA);
    k5a<<<g5a, 256, 0, stream>>>(wsF, wsI);
    k4b_thr<<<P_TOT / 256, 256, 0, stream>>>(wsF, wsI);
    dim3 g5c(P_TOT / RPB, JSP);
    k5c<<<g5c, 256, 0, stream>>>(wsF, wsI);
    k4d_final<<<P_TOT / TI, 256, 0, stream>>>(out, wsF, wsI);
}